// Round 9
// baseline (25.386 us; speedup 1.0000x reference)
//
#include <hip/hip_runtime.h>
#include <math.h>

// ComparingLoss: s = sum_{i<j, disc(i,j)} (d_i + d_j), out = s/T
// s = sum_i d_i * c_i, canonical predicate (xi>xj)^(li>lj) over ALL j.
//
// R9: ONE kernel, NO init (monotone counters + modular last-arrival: from any
// start value, 32 consecutive increments see each residue mod 32 exactly
// once). R8's failure was RELAXED atomics (one XCD's partials stale at the
// winner). Fix: ACQ_REL on both counter RMWs -> release publishes each
// block's partial store into the RMW chain; acquire at residue-31 observers
// (line leaders, winner) syncs with the whole release sequence and emits the
// cache invalidates needed across non-coherent XCD L2s. __syncthreads()
// extends visibility to the winner block's other waves.

#define T_N  8192
#define BLK  256                  // threads per block
#define IPT  8                    // consecutive i-rows per thread
#define JC   32                   // j-chunk per block
#define NIB  (T_N / (BLK * IPT))  // 4 i-blocks
#define NJC  (T_N / JC)           // 256 j-chunks
#define NBLK (NIB * NJC)          // 1024 blocks

typedef unsigned long long ull;

__global__ __launch_bounds__(BLK) void pair_single_kernel(
    const float* __restrict__ x, const float* __restrict__ lab,
    ull* __restrict__ cnt, float* __restrict__ partial,
    float* __restrict__ out) {
  __shared__ float2 js[JC];
  __shared__ float wsum[BLK / 64];
  __shared__ double dsum[BLK / 64];
  __shared__ int winner;

  const int tid = threadIdx.x;
  const int bid = blockIdx.y * NIB + blockIdx.x;
  const int i0 = blockIdx.x * (BLK * IPT) + tid * IPT;  // 8 consecutive rows
  const int j0 = blockIdx.y * JC;

  if (tid < JC) js[tid] = make_float2(x[j0 + tid], lab[j0 + tid]);
  if (tid == 0) winner = 0;

  const float4 xa = ((const float4*)&x[i0])[0];
  const float4 xb = ((const float4*)&x[i0])[1];
  const float4 la = ((const float4*)&lab[i0])[0];
  const float4 lb = ((const float4*)&lab[i0])[1];
  const float xi[IPT] = {xa.x, xa.y, xa.z, xa.w, xb.x, xb.y, xb.z, xb.w};
  const float li[IPT] = {la.x, la.y, la.z, la.w, lb.x, lb.y, lb.z, lb.w};
  __syncthreads();

  int cn[IPT] = {0, 0, 0, 0, 0, 0, 0, 0};
#pragma unroll 8
  for (int jj = 0; jj < JC; ++jj) {
    const float2 v = js[jj];  // broadcast ds_read_b64, conflict-free
#pragma unroll
    for (int k = 0; k < IPT; ++k)
      cn[k] += (int)((xi[k] > v.x) != (li[k] > v.y));
  }

  float val = 0.f;
#pragma unroll
  for (int k = 0; k < IPT; ++k)
    val += fabsf(xi[k] - li[k]) * (float)cn[k];

#pragma unroll
  for (int off = 32; off >= 1; off >>= 1) val += __shfl_down(val, off, 64);
  if ((tid & 63) == 0) wsum[tid >> 6] = val;
  __syncthreads();

  if (tid == 0) {
    const float s = wsum[0] + wsum[1] + wsum[2] + wsum[3];
    __hip_atomic_store(&partial[bid], s, __ATOMIC_RELAXED,
                       __HIP_MEMORY_SCOPE_AGENT);
    // release: publishes the partial store into the RMW chain;
    // acquire: on seeing residue 31, syncs with the whole chain.
    const ull o1 = __hip_atomic_fetch_add(&cnt[(bid & 31) * 16], 1ULL,
                                          __ATOMIC_ACQ_REL,
                                          __HIP_MEMORY_SCOPE_AGENT);
    if ((o1 & 31ULL) == 31ULL) {              // last arrival on this line
      const ull o2 = __hip_atomic_fetch_add(&cnt[512], 1ULL,
                                            __ATOMIC_ACQ_REL,
                                            __HIP_MEMORY_SCOPE_AGENT);
      if ((o2 & 31ULL) == 31ULL) winner = 1;  // last line done
    }
  }
  __syncthreads();  // extends tid0's acquired visibility block-wide

  if (winner) {
    const int base = tid * 4;
    double t = 0.0;
#pragma unroll
    for (int k = 0; k < 4; ++k)
      t += (double)__hip_atomic_load(&partial[base + k], __ATOMIC_RELAXED,
                                     __HIP_MEMORY_SCOPE_AGENT);
#pragma unroll
    for (int off = 32; off >= 1; off >>= 1) t += __shfl_down(t, off, 64);
    if ((tid & 63) == 0) dsum[tid >> 6] = t;
    __syncthreads();
    if (tid == 0)
      out[0] = (float)((dsum[0] + dsum[1] + dsum[2] + dsum[3]) / (double)T_N);
  }
}

extern "C" void kernel_launch(void* const* d_in, const int* in_sizes, int n_in,
                              void* d_out, int out_size, void* d_ws, size_t ws_size,
                              hipStream_t stream) {
  const float* x = (const float*)d_in[0];
  const float* lab = (const float*)d_in[1];
  float* out = (float*)d_out;
  ull* cnt = (ull*)d_ws;                          // 32 lines @128B + final
  float* partial = (float*)((char*)d_ws + 8192);  // 1024 floats

  dim3 grid(NIB, NJC);
  pair_single_kernel<<<grid, BLK, 0, stream>>>(x, lab, cnt, partial, out);
}